// Round 10
// baseline (518.774 us; speedup 1.0000x reference)
//
#include <hip/hip_runtime.h>
#include <cstdint>
#include <math.h>

// GREEN since r6. Ladder: r15 490 -> r17 326 (pk_fma full-rate) -> r19 285
// (DPP butterfly; 2 chains/wave; U streamed via remat coalesced loads).
// FAILED structures, each with a proven reason:
//  r20/r21/r22: 192 U floats in VGPRs -- RA caps ~136 here, always remats/
//    spills. r23: packed ws with 768B lane stride = UNCOALESCED (64 cache
//    lines/instr) -> 1468us. r24: U in LDS shared by 4 waves -> LDS BW is
//    per-wave (8 waves x 48KB = 384KB/CU/step at ~100B/cyc ~= 4000cyc) ->
//    344us. LDS has no cross-wave broadcast amortization.
// THIS ROUND r25 = r23's imm-offset idea with a COALESCED TRANSPOSED pack:
//  ws4[(c*3+g)*64 + j] = {U[4c+e][g*64+j]}e=0..3. Cross-lane: consecutive
//  float4s -> 1KB aligned segment/instr (ideal). Per-lane: 48 dwordx4 at
//  base + j*16 + (c*3+g)*1024 -> SGPR-add addressing, ~30 VALU total vs
//  r19's ~350. Issue/wave/step ~580 vs 850. Same values, same FMA order ->
//  absmax must stay 0.0. Everything else = r19 verbatim.
// Predict: dur 285 -> 205-245us, VALUBusy 65-75%, VGPR 60-110, LDS 4096.
// Failure (r23 cliff: VALU<40%, VGPR<50, dur>280) -> revert r19, roofline.
// EMPIRICAL RULES: only __launch_bounds__(64,1) gives the full reg budget;
// OccupancyPercent counter is gfx94x fallback (untrustworthy); occupancy is
// grid-capped at 2 waves/SIMD in the 64-thread structure.
// Locked-in: PRNG = partitionable threefry (key_t = tf((0,42),(0,t)); bits =
// o0^o1 of tf(key_t,(0,2s+cat))); f32 in/out; out = [4096*144][4096];
// decisions rounding-robust (6 arithmetic variants, bit-identical streams).

#define NSAMP 4096
#define NSTEP 144
#define HID 64
#define CPB 2            // chains per block (one wave)

typedef float v4f  __attribute__((ext_vector_type(4)));
typedef float v2f  __attribute__((ext_vector_type(2)));

// ---- JAX threefry2x32 (20 rounds, key-inject every 4) ----
__device__ __forceinline__ void threefry2x32(uint32_t k0, uint32_t k1,
                                             uint32_t x0, uint32_t x1,
                                             uint32_t& o0, uint32_t& o1) {
  const uint32_t ks0 = k0, ks1 = k1, ks2 = k0 ^ k1 ^ 0x1BD11BDAu;
  x0 += ks0; x1 += ks1;
#define TF_ROUND(d) { x0 += x1; x1 = (x1 << (d)) | (x1 >> (32 - (d))); x1 ^= x0; }
  TF_ROUND(13) TF_ROUND(15) TF_ROUND(26) TF_ROUND(6)
  x0 += ks1; x1 += ks2 + 1u;
  TF_ROUND(17) TF_ROUND(29) TF_ROUND(16) TF_ROUND(24)
  x0 += ks2; x1 += ks0 + 2u;
  TF_ROUND(13) TF_ROUND(15) TF_ROUND(26) TF_ROUND(6)
  x0 += ks0; x1 += ks1 + 3u;
  TF_ROUND(17) TF_ROUND(29) TF_ROUND(16) TF_ROUND(24)
  x0 += ks1; x1 += ks2 + 4u;
  TF_ROUND(13) TF_ROUND(15) TF_ROUND(26) TF_ROUND(6)
  x0 += ks2; x1 += ks0 + 5u;
#undef TF_ROUND
  o0 = x0; o1 = x1;
}

__device__ __forceinline__ float fsig(float x) {        // 1/(1+e^-x), stable
  return __builtin_amdgcn_rcpf(1.0f + __expf(-x));
}
__device__ __forceinline__ float ftanh(float x) {       // 1 - 2/(e^2x+1)
  const float e = __expf(2.0f * x);
  return 1.0f - 2.0f * __builtin_amdgcn_rcpf(e + 1.0f);
}

// Packed f32 FMA, chains (a,b) in (lo,hi). u-pair even-aligned; LO
// broadcasts its low element to both halves, HI the high one.
#define PKFMA_LO(acc, h2, up) \
  asm("v_pk_fma_f32 %0, %1, %2, %0 op_sel_hi:[1,0,1]" \
      : "+v"(acc) : "v"(h2), "v"(up));
#define PKFMA_HI(acc, h2, up) \
  asm("v_pk_fma_f32 %0, %1, %2, %0 op_sel:[0,1,0] op_sel_hi:[1,1,1]" \
      : "+v"(acc) : "v"(h2), "v"(up));

// DPP butterfly level: v += lane-swapped(v); bitwise == __shfl_xor(v,m)
// given the uniformity at each level (proven r19).
template <int CTRL>
__device__ __forceinline__ float dpp_add(float v) {
  union { float f; int i; } c; c.f = v;
  union { int i; float f; } r;
  r.i = __builtin_amdgcn_mov_dpp(c.i, CTRL, 0xF, 0xF, true);
  return v + r.f;
}
#define DPP_XOR1 0xB1
#define DPP_XOR2 0x4E
#define DPP_XOR4 0x141
#define DPP_XOR8 0x140

// ---- one-time coalesced U pack: ws4[(c*3+g)*64 + j] = {U[4c+e][g*64+j]} ----
__global__ void pack_kernel(const float* __restrict__ U,
                            float* __restrict__ ws) {
  const int idx = blockIdx.x * 256 + threadIdx.x;   // one per float4 (3072)
  if (idx < 16 * 3 * 64) {
    const int j = idx & 63;
    const int cg = idx >> 6;             // c*3 + g
    const int c = cg / 3, g = cg - 3 * c;
    float4 x;
    x.x = U[(4 * c + 0) * 192 + g * 64 + j];
    x.y = U[(4 * c + 1) * 192 + g * 64 + j];
    x.z = U[(4 * c + 2) * 192 + g * 64 + j];
    x.w = U[(4 * c + 3) * 192 + g * 64 + j];
    ((float4*)ws)[idx] = x;
  }
}

__global__ __launch_bounds__(64, 1) void vmc_kernel(
    const float* __restrict__ W, const float* __restrict__ Upk,
    const float* __restrict__ B, const float* __restrict__ Wd,
    const float* __restrict__ Bd, float* __restrict__ out) {
  const int j = threadIdx.x;           // hidden unit owned by this lane
  const int s_base = blockIdx.x * CPB; // first of 2 chains in this block

  __shared__ __align__(16) float2 hsh2[HID];      // h[unit] = {chain a, chain b}
  __shared__ uint2 kkeys[NSTEP];
  __shared__ float gsh[CPB * 2 * NSTEP];          // gumbels [c*288 + 2t + cat]

  // --- per-step keys: key_t = threefry((0,42),(0,t)) ---
#pragma unroll 1
  for (int t = j; t < NSTEP; t += HID) {
    uint32_t o0, o1;
    threefry2x32(0u, 42u, 0u, (uint32_t)t, o0, o1);
    kkeys[t].x = o0; kkeys[t].y = o1;
  }
  hsh2[j] = float2{0.0f, 0.0f};
  __syncthreads();

  // --- gumbels: EXACT path kept (f64 libm, one-time): bits = o0^o1 of
  // tf(key_t,(0,2s+cat)); u = bitcast(bits>>9|0x3f800000)-1 clamped tiny ---
#pragma unroll 1
  for (int id = j; id < CPB * 2 * NSTEP; id += HID) {
    const int c = id / 288;
    const int idx = id - c * 288;
    const uint2 kt = kkeys[idx >> 1];
    const uint32_t i = 2u * (uint32_t)(s_base + c) + (uint32_t)(idx & 1);
    uint32_t o0, o1;
    threefry2x32(kt.x, kt.y, 0u, i, o0, o1);
    const uint32_t bits = o0 ^ o1;
    union { uint32_t u; float f; } cv; cv.u = (bits >> 9) | 0x3F800000u;
    float uf = cv.f - 1.0f;
    uf = fmaxf(uf, 1.17549435e-38f);
    const float inner = (float)log((double)uf);
    gsh[id] = -(float)log((double)(-inner));
  }
  __syncthreads();

  // --- packed-U base: row (c*3+g) is 64 float4s; lane j reads element j.
  // Every load: 1KB aligned coalesced segment; per-lane addr = base + j*16
  // + imm/SGPR offset. ---
  const v4f* Up4 = (const v4f*)Upk;

  const float b1z = B[192 + j], b1r = B[256 + j], b1n = B[320 + j];
  const float b0z = B[j],       b0r = B[64 + j],  b0n = B[128 + j];
  const float xW0z = W[j]       + b0z, xW1z = W[192 + j] + b0z;
  const float xW0r = W[64 + j]  + b0r, xW1r = W[256 + j] + b0r;
  const float xW0n = W[128 + j] + b0n, xW1n = W[320 + j] + b0n;
  const float wdd = Wd[2*j + 1] - Wd[2*j];   // dense difference column
  const float bdd = Bd[1] - Bd[0];

  float ha = 0.0f, hb_ = 0.0f;
  float logPa = 0.0f, logPb = 0.0f;
  float axz = b0z, axr = b0r, axn = b0n;  // t=0: x=0 -> xm = b[0]
  float bxz = b0z, bxr = b0r, bxn = b0n;
  // loop-carried packed dot accumulators {chain a, chain b}; h_{-1}=0 -> 0
  v2f hz2 = {0.f, 0.f}, hr2 = {0.f, 0.f}, hn2 = {0.f, 0.f};

  for (int t = 0; t < NSTEP; ++t) {
    // ---- gates from the PREVIOUS iteration's dot (software pipeline) ----
    {
      const float az = axz + (hz2.x + b1z), ar = axr + (hr2.x + b1r);
      const float zz = fsig(az), rr = fsig(ar);
      const float hh = ftanh(axn + rr * (hn2.x + b1n));
      ha = zz * ha + (1.0f - zz) * hh;
    }
    {
      const float az = bxz + (hz2.y + b1z), ar = bxr + (hr2.y + b1r);
      const float zz = fsig(az), rr = fsig(ar);
      const float hh = ftanh(bxn + rr * (hn2.y + b1n));
      hb_ = zz * hb_ + (1.0f - zz) * hh;
    }
    hsh2[j] = float2{ha, hb_};   // single wave: LDS ops in program order

    // ---- dense: difference-reduction, butterfly m=1..32. Levels 1-8 via
    // DPP VALU (bit-exact), 16/32 via shfl. ----
    float da = ha * wdd, db = hb_ * wdd;
    da = dpp_add<DPP_XOR1>(da); db = dpp_add<DPP_XOR1>(db);
    da = dpp_add<DPP_XOR2>(da); db = dpp_add<DPP_XOR2>(db);
    da = dpp_add<DPP_XOR4>(da); db = dpp_add<DPP_XOR4>(db);
    da = dpp_add<DPP_XOR8>(da); db = dpp_add<DPP_XOR8>(db);
    da += __shfl_xor(da, 16, 64); db += __shfl_xor(db, 16, 64);
    da += __shfl_xor(da, 32, 64); db += __shfl_xor(db, 32, 64);

    int sma, smb;
    {
      const float d = da + bdd;
      const float p1 = fsig(d), p0 = fsig(-d);
      const float lp0 = __logf(1e-10f + p0);
      const float lp1 = __logf(1e-10f + p1);
      const float g0 = gsh[2*t], g1 = gsh[2*t + 1];
      sma = (lp1 + g1) > (lp0 + g0);
      logPa += sma ? lp1 : lp0;
      axz = sma ? xW1z : xW0z;
      axr = sma ? xW1r : xW0r;
      axn = sma ? xW1n : xW0n;
    }
    {
      const float d = db + bdd;
      const float p1 = fsig(d), p0 = fsig(-d);
      const float lp0 = __logf(1e-10f + p0);
      const float lp1 = __logf(1e-10f + p1);
      const float g0 = gsh[288 + 2*t], g1 = gsh[288 + 2*t + 1];
      smb = (lp1 + g1) > (lp0 + g0);
      logPb += smb ? lp1 : lp0;
      bxz = smb ? xW1z : xW0z;
      bxr = smb ? xW1r : xW0r;
      bxn = smb ? xW1n : xW0n;
    }
    if (j == 0) {
      out[(s_base + 0) * NSTEP + t] = sma ? 1.0f : 0.0f;
      out[(s_base + 1) * NSTEP + t] = smb ? 1.0f : 0.0f;
    }

    // ---- dot for NEXT step: hm = h_t @ U, k-ascending per half, packed
    // {a,b}. h pairs from LDS float2 broadcast; U via 48 coalesced
    // dwordx4 from the packed ws (q0/q1/q2 = Uz/Ur/Un of chunk c).
    // Same values, same per-half order as r19 -> bit-identical decisions. ----
    hz2 = v2f{0.f, 0.f}; hr2 = v2f{0.f, 0.f}; hn2 = v2f{0.f, 0.f};
#define SV2(x, a, b) __builtin_shufflevector(x, x, a, b)
#define DOTC(c_) \
    { const v4f hA = *(const v4f*)&hsh2[(c_)*4]; \
      const v4f hB = *(const v4f*)&hsh2[(c_)*4 + 2]; \
      const v4f q0 = Up4[((c_)*3 + 0) * 64 + j]; \
      const v4f q1 = Up4[((c_)*3 + 1) * 64 + j]; \
      const v4f q2 = Up4[((c_)*3 + 2) * 64 + j]; \
      const v2f h0  = SV2(hA, 0, 1); \
      const v2f h1  = SV2(hA, 2, 3); \
      const v2f h2_ = SV2(hB, 0, 1); \
      const v2f h3  = SV2(hB, 2, 3); \
      const v2f uz01 = SV2(q0, 0, 1), uz23 = SV2(q0, 2, 3); \
      const v2f ur01 = SV2(q1, 0, 1), ur23 = SV2(q1, 2, 3); \
      const v2f un01 = SV2(q2, 0, 1), un23 = SV2(q2, 2, 3); \
      PKFMA_LO(hz2, h0,  uz01) PKFMA_LO(hr2, h0,  ur01) PKFMA_LO(hn2, h0,  un01) \
      PKFMA_HI(hz2, h1,  uz01) PKFMA_HI(hr2, h1,  ur01) PKFMA_HI(hn2, h1,  un01) \
      PKFMA_LO(hz2, h2_, uz23) PKFMA_LO(hr2, h2_, ur23) PKFMA_LO(hn2, h2_, un23) \
      PKFMA_HI(hz2, h3,  uz23) PKFMA_HI(hr2, h3,  ur23) PKFMA_HI(hn2, h3,  un23) }
    DOTC(0)  DOTC(1)  DOTC(2)  DOTC(3)
    DOTC(4)  DOTC(5)  DOTC(6)  DOTC(7)
    DOTC(8)  DOTC(9)  DOTC(10) DOTC(11)
    DOTC(12) DOTC(13) DOTC(14) DOTC(15)
#undef DOTC
#undef SV2
  }

  if (j == 0) {
    *(float2*)&out[NSAMP * NSTEP + s_base] = float2{logPa, logPb};
  }
}

extern "C" void kernel_launch(void* const* d_in, const int* in_sizes, int n_in,
                              void* d_out, int out_size, void* d_ws, size_t ws_size,
                              hipStream_t stream) {
  // inputs (setup_inputs order): nsamples(1), W(2x192), U(64x192), b(2x192),
  // Wd(64x2), bd(2) — float32
  const float* W  = (const float*)d_in[1];
  const float* U  = (const float*)d_in[2];
  const float* B  = (const float*)d_in[3];
  const float* Wd = (const float*)d_in[4];
  const float* Bd = (const float*)d_in[5];
  float* ws = (float*)d_ws;  // needs 48KB for packed U
  pack_kernel<<<dim3(12), dim3(256), 0, stream>>>(U, ws);
  vmc_kernel<<<dim3(NSAMP / CPB), dim3(HID), 0, stream>>>(
      W, ws, B, Wd, Bd, (float*)d_out);
}

// Round 11
// 371.259 us; speedup vs baseline: 1.3973x; 1.3973x over previous
//
#include <hip/hip_runtime.h>
#include <cstdint>
#include <math.h>

// GREEN since r6. Ladder: r15 490 -> r17 326 (pk_fma full-rate) -> r19 285
// (DPP butterfly; 2 chains/wave; U streamed via compiler-remat global
// loads -- the addr-VALU stream IS the latency hider).
// FAILED structures, each with a proven cause: r20/21/22 reg-pin (RA caps
// ~136); r23 uncoalesced pack (1468us); r24 LDS-shared U (LDS BW is
// per-wave, 344us); r25 coalesced pack (518us: few instrs + 80 VGPR =
// loads can't stay in flight; L1 thrashes at 48KB working set).
// LAW: every wave pulls 48KB U/step; traffic/CU = waves/CU x 48KB; with
// 4096 chains, waves = 4096/CPW -> ONLY more chains/wave cuts traffic.
// CPW=2: 384KB/CU/step (~2850cyc L2 floor under r19's 4750 wall).
// THIS ROUND r26: CPW=4 inside r19's exact codegen envelope: 64-thr
// single-wave blocks, launch_bounds(64,1), SAME v16f LOADB remat U stream,
// DPP butterfly, pk dot. Grid 1024 -> 1 wave/SIMD. Each U element feeds 4
// chains (pk groups {a,b},{c,d} off a float4 h-broadcast). Issue ~1100
// instr/step/wave (~2200cyc) vs memory floor ~1400cyc -> wall ~2300-2800
// vs r19 4750. Per-chain arithmetic/FMA order/PRNG bit-identical ->
// absmax must stay 0.0.
// Predict: dur 285 -> 150-210us, VGPR 150-220, VALUBusy 65-85%. Failure:
// dur>285 + VALUBusy<50% = 1-wave/SIMD latency exposure -> r19 is the
// structural optimum; re-examine ceiling.
// Locked-in: PRNG = partitionable threefry (key_t = tf((0,42),(0,t)); bits =
// o0^o1 of tf(key_t,(0,2s+cat))); f32 in/out; out = [4096*144][4096];
// decisions rounding-robust (6 arithmetic variants, bit-identical streams).

#define NSAMP 4096
#define NSTEP 144
#define HID 64
#define CPW 4            // chains per wave (one wave per block)

typedef float v16f __attribute__((ext_vector_type(16)));
typedef float v4f  __attribute__((ext_vector_type(4)));
typedef float v2f  __attribute__((ext_vector_type(2)));

// ---- JAX threefry2x32 (20 rounds, key-inject every 4) ----
__device__ __forceinline__ void threefry2x32(uint32_t k0, uint32_t k1,
                                             uint32_t x0, uint32_t x1,
                                             uint32_t& o0, uint32_t& o1) {
  const uint32_t ks0 = k0, ks1 = k1, ks2 = k0 ^ k1 ^ 0x1BD11BDAu;
  x0 += ks0; x1 += ks1;
#define TF_ROUND(d) { x0 += x1; x1 = (x1 << (d)) | (x1 >> (32 - (d))); x1 ^= x0; }
  TF_ROUND(13) TF_ROUND(15) TF_ROUND(26) TF_ROUND(6)
  x0 += ks1; x1 += ks2 + 1u;
  TF_ROUND(17) TF_ROUND(29) TF_ROUND(16) TF_ROUND(24)
  x0 += ks2; x1 += ks0 + 2u;
  TF_ROUND(13) TF_ROUND(15) TF_ROUND(26) TF_ROUND(6)
  x0 += ks0; x1 += ks1 + 3u;
  TF_ROUND(17) TF_ROUND(29) TF_ROUND(16) TF_ROUND(24)
  x0 += ks1; x1 += ks2 + 4u;
  TF_ROUND(13) TF_ROUND(15) TF_ROUND(26) TF_ROUND(6)
  x0 += ks2; x1 += ks0 + 5u;
#undef TF_ROUND
  o0 = x0; o1 = x1;
}

__device__ __forceinline__ float fsig(float x) {        // 1/(1+e^-x), stable
  return __builtin_amdgcn_rcpf(1.0f + __expf(-x));
}
__device__ __forceinline__ float ftanh(float x) {       // 1 - 2/(e^2x+1)
  const float e = __expf(2.0f * x);
  return 1.0f - 2.0f * __builtin_amdgcn_rcpf(e + 1.0f);
}

// Packed f32 FMA, one chain-pair in (lo,hi). u-pair even-aligned; LO
// broadcasts its low element to both halves, HI the high one.
#define PKFMA_LO(acc, h2, up) \
  asm("v_pk_fma_f32 %0, %1, %2, %0 op_sel_hi:[1,0,1]" \
      : "+v"(acc) : "v"(h2), "v"(up));
#define PKFMA_HI(acc, h2, up) \
  asm("v_pk_fma_f32 %0, %1, %2, %0 op_sel:[0,1,0] op_sel_hi:[1,1,1]" \
      : "+v"(acc) : "v"(h2), "v"(up));

// DPP butterfly level: v += lane-swapped(v); bitwise == __shfl_xor(v,m)
// given the uniformity at each level (proven r19).
template <int CTRL>
__device__ __forceinline__ float dpp_add(float v) {
  union { float f; int i; } c; c.f = v;
  union { int i; float f; } r;
  r.i = __builtin_amdgcn_mov_dpp(c.i, CTRL, 0xF, 0xF, true);
  return v + r.f;
}
#define DPP_XOR1 0xB1
#define DPP_XOR2 0x4E
#define DPP_XOR4 0x141
#define DPP_XOR8 0x140

__global__ __launch_bounds__(64, 1) void vmc_kernel(
    const float* __restrict__ W, const float* __restrict__ U,
    const float* __restrict__ B, const float* __restrict__ Wd,
    const float* __restrict__ Bd, float* __restrict__ out) {
  const int j = threadIdx.x;           // hidden unit owned by this lane
  const int s_base = blockIdx.x * CPW; // first of this wave's 4 chains

  __shared__ __align__(16) float4 hsh4[HID];      // h[unit] = {a,b,c,d}
  __shared__ uint2 kkeys[NSTEP];
  __shared__ float gsh[CPW * 2 * NSTEP];          // gumbels [c*288 + 2t + cat]

  // --- per-step keys: key_t = threefry((0,42),(0,t)) ---
#pragma unroll 1
  for (int t = j; t < NSTEP; t += HID) {
    uint32_t o0, o1;
    threefry2x32(0u, 42u, 0u, (uint32_t)t, o0, o1);
    kkeys[t].x = o0; kkeys[t].y = o1;
  }
  hsh4[j] = float4{0.0f, 0.0f, 0.0f, 0.0f};
  __syncthreads();

  // --- gumbels: EXACT path kept (f64 libm, one-time): bits = o0^o1 of
  // tf(key_t,(0,2s+cat)); u = bitcast(bits>>9|0x3f800000)-1 clamped tiny ---
#pragma unroll 1
  for (int id = j; id < CPW * 2 * NSTEP; id += HID) {
    const int c = id / 288;
    const int idx = id - c * 288;
    const uint2 kt = kkeys[idx >> 1];
    const uint32_t i = 2u * (uint32_t)(s_base + c) + (uint32_t)(idx & 1);
    uint32_t o0, o1;
    threefry2x32(kt.x, kt.y, 0u, i, o0, o1);
    const uint32_t bits = o0 ^ o1;
    union { uint32_t u; float f; } cv; cv.u = (bits >> 9) | 0x3F800000u;
    float uf = cv.f - 1.0f;
    uf = fmaxf(uf, 1.17549435e-38f);
    const float inner = (float)log((double)uf);
    gsh[id] = -(float)log((double)(-inner));
  }
  __syncthreads();

  // --- Uz, Ur, Un columns for unit j (r19 pattern: compiler remat-streams
  // these inside the loop; the addressing VALU doubles as latency hiding) ---
  v16f uz0, uz1, uz2, uz3, ur0, ur1, ur2, ur3, un0, un1, un2, un3;
#define LOADB(v, r, off) \
  { _Pragma("unroll") for (int e = 0; e < 16; ++e) v[e] = U[((r)*16 + e)*192 + (off) + j]; }
  LOADB(uz0, 0, 0)    LOADB(uz1, 1, 0)    LOADB(uz2, 2, 0)    LOADB(uz3, 3, 0)
  LOADB(ur0, 0, 64)   LOADB(ur1, 1, 64)   LOADB(ur2, 2, 64)   LOADB(ur3, 3, 64)
  LOADB(un0, 0, 128)  LOADB(un1, 1, 128)  LOADB(un2, 2, 128)  LOADB(un3, 3, 128)
#undef LOADB

  const float b1z = B[192 + j], b1r = B[256 + j], b1n = B[320 + j];
  const float b0z = B[j],       b0r = B[64 + j],  b0n = B[128 + j];
  const float xW0z = W[j]       + b0z, xW1z = W[192 + j] + b0z;
  const float xW0r = W[64 + j]  + b0r, xW1r = W[256 + j] + b0r;
  const float xW0n = W[128 + j] + b0n, xW1n = W[320 + j] + b0n;
  const float wdd = Wd[2*j + 1] - Wd[2*j];   // dense difference column
  const float bdd = Bd[1] - Bd[0];

  float hcur[CPW], logP[CPW], axz[CPW], axr[CPW], axn[CPW];
#pragma unroll
  for (int cc = 0; cc < CPW; ++cc) {
    hcur[cc] = 0.0f; logP[cc] = 0.0f;
    axz[cc] = b0z; axr[cc] = b0r; axn[cc] = b0n;  // t=0: x=0 -> xm = b[0]
  }
  // loop-carried packed dot accumulators {a,b} and {c,d}; h_{-1}=0 -> 0
  v2f hzAB = {0.f, 0.f}, hzCD = {0.f, 0.f};
  v2f hrAB = {0.f, 0.f}, hrCD = {0.f, 0.f};
  v2f hnAB = {0.f, 0.f}, hnCD = {0.f, 0.f};

  for (int t = 0; t < NSTEP; ++t) {
    // ---- gates from the PREVIOUS iteration's dot (software pipeline) ----
#define GATE(cc, hzv, hrv, hnv) { \
      const float az = axz[cc] + ((hzv) + b1z), ar = axr[cc] + ((hrv) + b1r); \
      const float zz = fsig(az), rr = fsig(ar); \
      const float hh = ftanh(axn[cc] + rr * ((hnv) + b1n)); \
      hcur[cc] = zz * hcur[cc] + (1.0f - zz) * hh; }
    GATE(0, hzAB.x, hrAB.x, hnAB.x)
    GATE(1, hzAB.y, hrAB.y, hnAB.y)
    GATE(2, hzCD.x, hrCD.x, hnCD.x)
    GATE(3, hzCD.y, hrCD.y, hnCD.y)
#undef GATE
    hsh4[j] = float4{hcur[0], hcur[1], hcur[2], hcur[3]};  // single wave:
    // LDS ops program-ordered; broadcast reads below see this write.

    // ---- dense: difference-reduction, butterfly m=1..32 per chain.
    // Levels 1-8 via DPP VALU (bit-exact), 16/32 via shfl. ----
    int smv[CPW];
#define CHAIN_DEC(cc) { \
      float d_ = hcur[cc] * wdd; \
      d_ = dpp_add<DPP_XOR1>(d_); d_ = dpp_add<DPP_XOR2>(d_); \
      d_ = dpp_add<DPP_XOR4>(d_); d_ = dpp_add<DPP_XOR8>(d_); \
      d_ += __shfl_xor(d_, 16, 64); d_ += __shfl_xor(d_, 32, 64); \
      const float d = d_ + bdd; \
      const float p1 = fsig(d), p0 = fsig(-d); \
      const float lp0 = __logf(1e-10f + p0); \
      const float lp1 = __logf(1e-10f + p1); \
      const float g0 = gsh[(cc)*288 + 2*t], g1 = gsh[(cc)*288 + 2*t + 1]; \
      const int sm = (lp1 + g1) > (lp0 + g0); \
      logP[cc] += sm ? lp1 : lp0; \
      axz[cc] = sm ? xW1z : xW0z; \
      axr[cc] = sm ? xW1r : xW0r; \
      axn[cc] = sm ? xW1n : xW0n; \
      smv[cc] = sm; }
    CHAIN_DEC(0) CHAIN_DEC(1) CHAIN_DEC(2) CHAIN_DEC(3)
#undef CHAIN_DEC
    if (j == 0) {
      out[(s_base + 0) * NSTEP + t] = smv[0] ? 1.0f : 0.0f;
      out[(s_base + 1) * NSTEP + t] = smv[1] ? 1.0f : 0.0f;
      out[(s_base + 2) * NSTEP + t] = smv[2] ? 1.0f : 0.0f;
      out[(s_base + 3) * NSTEP + t] = smv[3] ? 1.0f : 0.0f;
    }

    // ---- dot for NEXT step: hm = h_t @ U, k-ascending per accumulator,
    // chains packed {a,b} + {c,d} off one float4 h-broadcast. U elements
    // from the remat v16f stream (each feeds BOTH pk groups). Same values,
    // same per-chain order as r19 -> bit-identical decisions. ----
    hzAB = v2f{0.f, 0.f}; hzCD = v2f{0.f, 0.f};
    hrAB = v2f{0.f, 0.f}; hrCD = v2f{0.f, 0.f};
    hnAB = v2f{0.f, 0.f}; hnCD = v2f{0.f, 0.f};
#define SV2(x, a, b) __builtin_shufflevector(x, x, a, b)
#define DOTC(uzv, urv, unv, blk, cc) \
    { const int c_ = (blk)*4 + (cc); \
      const v4f h40 = *(const v4f*)&hsh4[c_*4 + 0]; \
      const v4f h41 = *(const v4f*)&hsh4[c_*4 + 1]; \
      const v4f h42 = *(const v4f*)&hsh4[c_*4 + 2]; \
      const v4f h43 = *(const v4f*)&hsh4[c_*4 + 3]; \
      const int e_ = (cc)*4; \
      const v2f uz01 = SV2(uzv, e_+0, e_+1), uz23 = SV2(uzv, e_+2, e_+3); \
      const v2f ur01 = SV2(urv, e_+0, e_+1), ur23 = SV2(urv, e_+2, e_+3); \
      const v2f un01 = SV2(unv, e_+0, e_+1), un23 = SV2(unv, e_+2, e_+3); \
      { const v2f hab = SV2(h40, 0, 1), hcd = SV2(h40, 2, 3); \
        PKFMA_LO(hzAB, hab, uz01) PKFMA_LO(hzCD, hcd, uz01) \
        PKFMA_LO(hrAB, hab, ur01) PKFMA_LO(hrCD, hcd, ur01) \
        PKFMA_LO(hnAB, hab, un01) PKFMA_LO(hnCD, hcd, un01) } \
      { const v2f hab = SV2(h41, 0, 1), hcd = SV2(h41, 2, 3); \
        PKFMA_HI(hzAB, hab, uz01) PKFMA_HI(hzCD, hcd, uz01) \
        PKFMA_HI(hrAB, hab, ur01) PKFMA_HI(hrCD, hcd, ur01) \
        PKFMA_HI(hnAB, hab, un01) PKFMA_HI(hnCD, hcd, un01) } \
      { const v2f hab = SV2(h42, 0, 1), hcd = SV2(h42, 2, 3); \
        PKFMA_LO(hzAB, hab, uz23) PKFMA_LO(hzCD, hcd, uz23) \
        PKFMA_LO(hrAB, hab, ur23) PKFMA_LO(hrCD, hcd, ur23) \
        PKFMA_LO(hnAB, hab, un23) PKFMA_LO(hnCD, hcd, un23) } \
      { const v2f hab = SV2(h43, 0, 1), hcd = SV2(h43, 2, 3); \
        PKFMA_HI(hzAB, hab, uz23) PKFMA_HI(hzCD, hcd, uz23) \
        PKFMA_HI(hrAB, hab, ur23) PKFMA_HI(hrCD, hcd, ur23) \
        PKFMA_HI(hnAB, hab, un23) PKFMA_HI(hnCD, hcd, un23) } }
#define DOTBLK(uzv, urv, unv, blk) \
    DOTC(uzv, urv, unv, blk, 0) DOTC(uzv, urv, unv, blk, 1) \
    DOTC(uzv, urv, unv, blk, 2) DOTC(uzv, urv, unv, blk, 3)
    DOTBLK(uz0, ur0, un0, 0)
    DOTBLK(uz1, ur1, un1, 1)
    DOTBLK(uz2, ur2, un2, 2)
    DOTBLK(uz3, ur3, un3, 3)
#undef DOTBLK
#undef DOTC
#undef SV2
  }

  if (j == 0) {
    *(float4*)&out[NSAMP * NSTEP + s_base] =
        make_float4(logP[0], logP[1], logP[2], logP[3]);
  }
}

extern "C" void kernel_launch(void* const* d_in, const int* in_sizes, int n_in,
                              void* d_out, int out_size, void* d_ws, size_t ws_size,
                              hipStream_t stream) {
  // inputs (setup_inputs order): nsamples(1), W(2x192), U(64x192), b(2x192),
  // Wd(64x2), bd(2) — float32
  const float* W  = (const float*)d_in[1];
  const float* U  = (const float*)d_in[2];
  const float* B  = (const float*)d_in[3];
  const float* Wd = (const float*)d_in[4];
  const float* Bd = (const float*)d_in[5];
  vmc_kernel<<<dim3(NSAMP / CPW), dim3(HID), 0, stream>>>(
      W, U, B, Wd, Bd, (float*)d_out);
}